// Round 6
// baseline (421.275 us; speedup 1.0000x reference)
//
#include <hip/hip_runtime.h>
#include <cstdint>
#include <cstddef>

// ---------------- problem constants ----------------
static constexpr int NB  = 8;     // batch
static constexpr int S   = 512;   // seq len
static constexpr int HID = 1024;
static constexpr int NH  = 16;    // heads
static constexpr int DH  = 64;    // head dim
static constexpr int P2  = 1024;  // 2*ATT_SPAN

static constexpr float INV_S1 = 0.14433756729740643f;  // 1/sqrt(3*H)

typedef __bf16 v8bf  __attribute__((ext_vector_type(8)));
typedef __bf16 v4bf  __attribute__((ext_vector_type(4)));
typedef float  f32x4 __attribute__((ext_vector_type(4)));

#define MFMA16(acc, a, b) acc = __builtin_amdgcn_mfma_f32_16x16x32_bf16(a, b, acc, 0, 0, 0)

// direct global->LDS DMA, 16B per lane; LDS dest = uniform base + lane*16
#define GLOAD_LDS16(gp, lp) __builtin_amdgcn_global_load_lds( \
    (const __attribute__((address_space(1))) void*)(gp), \
    (__attribute__((address_space(3))) void*)(lp), 16, 0, 0)

// ---------------- fused cast fp32 -> bf16 over all 6 inputs ----------------
// ws bf16 layout (elements): [X 4M][Wq 1M][Wk 1M][Wv 1M][Wpk 1M][rel 1M] = 9M
__global__ void castall(const float* __restrict__ x,  const float* __restrict__ wq,
                        const float* __restrict__ wk, const float* __restrict__ wv,
                        const float* __restrict__ wpk, const float* __restrict__ rel,
                        __bf16* __restrict__ ob) {
  size_t e = ((size_t)blockIdx.x * 256 + threadIdx.x) * 4;
  if (e >= 9437184) return;
  const float* src; size_t off;
  if (e < 4194304) { src = x; off = e; }
  else {
    int r = (int)((e - 4194304) >> 20);
    off = (e - 4194304) & 1048575;
    src = (r == 0) ? wq : (r == 1) ? wk : (r == 2) ? wv : (r == 3) ? wpk : rel;
  }
  float4 v = *(const float4*)(src + off);
  v4bf o;
  o[0] = (__bf16)v.x; o[1] = (__bf16)v.y; o[2] = (__bf16)v.z; o[3] = (__bf16)v.w;
  *(v4bf*)(ob + e) = o;
}

// ---------------- projection GEMM, bf16, BK=64, global_load_lds staging ------
// C = A @ W^T + bias. z=0: Q (scaled INV_S1) -> [b][h][s][d]; z=1: K -> same;
// z=2: V -> [b][h][d][s] (transposed); z=3: pos (scaled INV_S1) -> [h][p][d].
// LDS tiles UNPADDED stride 64 (global_load_lds needs contiguous lane order);
// k-segment XOR-swizzled by row&7 at the global source so ds_read_b128 of
// fragments is ~2-way conflict max.
__launch_bounds__(256, 4)
__global__ void proj_gemm(const __bf16* __restrict__ Xb, const __bf16* __restrict__ Rb,
                          const __bf16* __restrict__ Wqb, const __bf16* __restrict__ Wkb,
                          const __bf16* __restrict__ Wvb, const __bf16* __restrict__ Wpkb,
                          const float* __restrict__ bq, const float* __restrict__ bk_,
                          const float* __restrict__ bv_, const float* __restrict__ bpk,
                          __bf16* __restrict__ qo, __bf16* __restrict__ ko,
                          __bf16* __restrict__ vto, __bf16* __restrict__ po) {
  const int z = blockIdx.z;
  const __bf16* A; const __bf16* W; const float* bias; __bf16* out; int M; float osc;
  if      (z == 0) { A = Xb; W = Wqb;  bias = bq;  out = qo;  M = 4096; osc = INV_S1; }
  else if (z == 1) { A = Xb; W = Wkb;  bias = bk_; out = ko;  M = 4096; osc = 1.0f; }
  else if (z == 2) { A = Xb; W = Wvb;  bias = bv_; out = vto; M = 4096; osc = 1.0f; }
  else             { A = Rb; W = Wpkb; bias = bpk; out = po;  M = 1024; osc = INV_S1; }
  const int m0 = blockIdx.x * 128;
  if (m0 >= M) return;
  const int n0 = blockIdx.y * 128;
  const int K = 1024;

  __shared__ __bf16 Al[128 * 64];  // unpadded; phys seg = seg ^ (row&7)
  __shared__ __bf16 Bl[128 * 64];

  const int t = threadIdx.x;
  const int w = t >> 6, lane = t & 63, q4 = lane >> 4, cc = lane & 15;
  const int wm = w >> 1, wn = w & 1;
  // staging geometry: wave w stages rows [w*32, w*32+32), 4 issues of 8 rows
  const int srow_in = lane >> 3;              // 0..7 within issue
  const int sseg    = ((lane & 7) ^ srow_in) * 8;  // XOR-swizzled k-chunk

  f32x4 acc[4][4] = {};

  for (int k0 = 0; k0 < K; k0 += 64) {
    __syncthreads();
    #pragma unroll
    for (int i = 0; i < 4; i++) {
      int rr = w * 32 + i * 8;                 // uniform per wave-issue
      int gr = rr + srow_in;
      GLOAD_LDS16(&A[(size_t)(m0 + gr) * K + k0 + sseg], &Al[rr * 64]);
      GLOAD_LDS16(&W[(size_t)(n0 + gr) * K + k0 + sseg], &Bl[rr * 64]);
    }
    __syncthreads();
    #pragma unroll
    for (int kk = 0; kk < 2; kk++) {
      v8bf af[4], bfg[4];
      const int phys = ((4 * kk + q4) ^ (cc & 7)) * 8;
      #pragma unroll
      for (int mt = 0; mt < 4; mt++)
        af[mt] = *(const v8bf*)(&Al[(wm * 64 + mt * 16 + cc) * 64 + phys]);
      #pragma unroll
      for (int nt = 0; nt < 4; nt++)
        bfg[nt] = *(const v8bf*)(&Bl[(wn * 64 + nt * 16 + cc) * 64 + phys]);
      #pragma unroll
      for (int mt = 0; mt < 4; mt++)
        #pragma unroll
        for (int nt = 0; nt < 4; nt++)
          MFMA16(acc[mt][nt], af[mt], bfg[nt]);
    }
  }

  #pragma unroll
  for (int mt = 0; mt < 4; mt++) {
    #pragma unroll
    for (int nt = 0; nt < 4; nt++) {
      int n = n0 + wn * 64 + nt * 16 + cc;
      float bsv = bias[n];
      if (z == 2) {
        int m_base = m0 + wm * 64 + mt * 16 + q4 * 4;
        int bb = m_base >> 9, ss = m_base & 511, hh = n >> 6, dd = n & 63;
        v4bf st;
        st[0] = (__bf16)(acc[mt][nt][0] + bsv);
        st[1] = (__bf16)(acc[mt][nt][1] + bsv);
        st[2] = (__bf16)(acc[mt][nt][2] + bsv);
        st[3] = (__bf16)(acc[mt][nt][3] + bsv);
        *(v4bf*)(&out[(((size_t)bb * 16 + hh) * 64 + dd) * 512 + ss]) = st;
      } else {
        #pragma unroll
        for (int r = 0; r < 4; r++) {
          int m = m0 + wm * 64 + mt * 16 + q4 * 4 + r;
          float val = (acc[mt][nt][r] + bsv) * osc;
          size_t idx;
          if (z < 2)
            idx = ((size_t)(m >> 9) * 16 + (n >> 6)) * (512 * 64) + (size_t)(m & 511) * 64 + (n & 63);
          else
            idx = (size_t)(n >> 6) * (1024 * 64) + (size_t)m * 64 + (n & 63);
          out[idx] = (__bf16)val;
        }
      }
    }
  }
}

// ---------------- fused disentangled attention: ZERO barriers ----------------
// grid (4, NB*NH), 512 threads = 8 free-running waves; wave w owns i-rows
// [i0+16w, i0+16w+16). All LDS wave-private, single buffer Sb (34816 B ->
// 4 blocks/CU). Per jt, same-wave in-order LDS sequence:
//   scatter G/H -> read scores -> overwrite slots 0..63 with probs -> PV read.
// Q,pos pre-scaled by 1/sqrt(48); G carries residual sqrt(3)/2.
__launch_bounds__(512, 8)
__global__ void attn(const __bf16* __restrict__ qb, const __bf16* __restrict__ kb,
                     const __bf16* __restrict__ vtb, const __bf16* __restrict__ posb,
                     const float* __restrict__ mask, float* __restrict__ out) {
  const int bh = blockIdx.y, b = bh >> 4, h = bh & 15;
  const int i0 = blockIdx.x * 128;

  __shared__ __bf16 Sb[128 * 136];   // [a][slot]: G at jj*2, H at jj*2+1, probs at 0..63

  const int t = threadIdx.x, w = t >> 6, lane = t & 63, q4 = lane >> 4, cc = lane & 15;
  const int arow = w * 16;
  const size_t bho = (size_t)bh * (S * DH);
  const __bf16* qp  = qb  + bho;
  const __bf16* kp  = kb  + bho;
  const __bf16* vtp = vtb + bho;   // [d][s]
  const __bf16* pp  = posb + (size_t)h * (P2 * DH);

  v8bf aq0 = *(const v8bf*)(&qp[(size_t)(i0 + arow + cc) * DH + q4 * 8]);
  v8bf aq1 = *(const v8bf*)(&qp[(size_t)(i0 + arow + cc) * DH + 32 + q4 * 8]);

  f32x4 Oc[4] = {};
  float mrow[4], lrow[4];
  #pragma unroll
  for (int r = 0; r < 4; r++) { mrow[r] = -__builtin_inff(); lrow[r] = 0.f; }

#define LDP(d0, d1, U) { int p_ = pw0 + 16 * (U) + cc; p_ = min(max(p_, 0), P2 - 1); \
  const __bf16* pr_ = &pp[(size_t)p_ * DH + q4 * 8]; \
  d0 = *(const v8bf*)pr_; d1 = *(const v8bf*)(pr_ + 32); }
#define LDK(d0, d1, NT) { const __bf16* kr_ = &kp[(size_t)(j0 + (NT) * 16 + cc) * DH + q4 * 8]; \
  d0 = *(const v8bf*)kr_; d1 = *(const v8bf*)(kr_ + 32); }
#define GT(U, P0, P1) { f32x4 g_ = {}; MFMA16(g_, aq0, P0); MFMA16(g_, aq1, P1); \
  _Pragma("unroll") for (int r_ = 0; r_ < 4; r_++) { \
    int jj_ = q4 * 4 + r_ - 16 * (U) - cc + 63; \
    if ((unsigned)jj_ < 64u) Sb[(arow + q4 * 4 + r_) * 136 + jj_ * 2] = (__bf16)(g_[r_] * 0.8660254f); } }
#define HT(U, NT, P0, P1, K0, K1) { f32x4 h_ = {}; MFMA16(h_, P0, K0); MFMA16(h_, P1, K1); \
  _Pragma("unroll") for (int r_ = 0; r_ < 4; r_++) { \
    int ar_ = 16 * (U) + q4 * 4 + r_ + 16 * (NT) + cc - 63; \
    if ((unsigned)ar_ < 16u) Sb[(arow + ar_) * 136 + (16 * (NT) + cc) * 2 + 1] = (__bf16)h_[r_]; } }
#define CT(NT, K0, K1) { f32x4 c_ = {}; MFMA16(c_, aq0, K0); MFMA16(c_, aq1, K1); accc[NT] = c_; }

  for (int jt = 0; jt < 8; jt++) {
    const int j0 = jt * 64;
    const int pw0 = i0 + arow - j0 + 449;  // band-local rho=0 (clamp covers p==1024)

    float mk[4];
    #pragma unroll
    for (int nt = 0; nt < 4; nt++) mk[nt] = mask[(size_t)b * S + j0 + nt * 16 + cc];

    f32x4 accc[4];
    v8bf p40,p41,p30,p31,p20,p21,p10,p11,p00,p01;
    v8bf k00,k01,k10,k11,k20,k21,k30,k31;

    LDP(p40, p41, 4); LDK(k00, k01, 0);
    LDP(p30, p31, 3); LDK(k10, k11, 1);
    GT(4, p40, p41); HT(4, 0, p40, p41, k00, k01); CT(0, k00, k01);
    LDP(p20, p21, 2); LDK(k20, k21, 2);
    GT(3, p30, p31); HT(3, 0, p30, p31, k00, k01); HT(3, 1, p30, p31, k10, k11); CT(1, k10, k11);
    LDP(p10, p11, 1); LDK(k30, k31, 3);
    GT(2, p20, p21); HT(2, 1, p20, p21, k10, k11); HT(2, 2, p20, p21, k20, k21); CT(2, k20, k21);
    LDP(p00, p01, 0);
    GT(1, p10, p11); HT(1, 2, p10, p11, k20, k21); HT(1, 3, p10, p11, k30, k31); CT(3, k30, k31);
    GT(0, p00, p01); HT(0, 3, p00, p01, k30, k31);

    // assemble scores (typed bf16 reads of G/H — same type as writes) + softmax
    float sc[4][4];
    float tmax[4] = { -__builtin_inff(), -__builtin_inff(), -__builtin_inff(), -__builtin_inff() };
    #pragma unroll
    for (int nt = 0; nt < 4; nt++) {
      int jj = nt * 16 + cc;
      #pragma unroll
      for (int r = 0; r < 4; r++) {
        const __bf16* slot = &Sb[(arow + q4 * 4 + r) * 136 + jj * 2];
        float s = accc[nt][r] + (float)slot[0] + (float)slot[1] + mk[nt];
        sc[nt][r] = s;
        tmax[r] = fmaxf(tmax[r], s);
      }
    }
    #pragma unroll
    for (int off = 1; off < 16; off <<= 1)
      #pragma unroll
      for (int r = 0; r < 4; r++) tmax[r] = fmaxf(tmax[r], __shfl_xor(tmax[r], off, 64));

    // V fragments (late to bound register pressure; hidden under softmax)
    v8bf vf[2][4];
    #pragma unroll
    for (int kk = 0; kk < 2; kk++)
      #pragma unroll
      for (int dt = 0; dt < 4; dt++)
        vf[kk][dt] = *(const v8bf*)(&vtp[(size_t)(dt * 16 + cc) * S + j0 + kk * 32 + q4 * 8]);

    float alpha[4], psum[4];
    #pragma unroll
    for (int r = 0; r < 4; r++) {
      float mnew = fmaxf(mrow[r], tmax[r]);
      alpha[r] = __expf(mrow[r] - mnew);
      mrow[r] = mnew;
      psum[r] = 0.f;
    }
    // overwrite dead G/H slots 0..63 with probs (same-wave in-order LDS)
    #pragma unroll
    for (int nt = 0; nt < 4; nt++)
      #pragma unroll
      for (int r = 0; r < 4; r++) {
        float p = __expf(sc[nt][r] - mrow[r]);
        psum[r] += p;
        Sb[(arow + q4 * 4 + r) * 136 + nt * 16 + cc] = (__bf16)p;
      }
    #pragma unroll
    for (int off = 1; off < 16; off <<= 1)
      #pragma unroll
      for (int r = 0; r < 4; r++) psum[r] += __shfl_xor(psum[r], off, 64);
    #pragma unroll
    for (int r = 0; r < 4; r++) lrow[r] = lrow[r] * alpha[r] + psum[r];
    #pragma unroll
    for (int dt = 0; dt < 4; dt++)
      #pragma unroll
      for (int r = 0; r < 4; r++) Oc[dt][r] *= alpha[r];

    // PV: probs A-frag read from Sb rows (16B-aligned: 136*2=272 = 16*17)
    #pragma unroll
    for (int kk = 0; kk < 2; kk++) {
      v8bf ap = *(const v8bf*)(&Sb[(arow + cc) * 136 + kk * 32 + q4 * 8]);
      #pragma unroll
      for (int dt = 0; dt < 4; dt++)
        MFMA16(Oc[dt], ap, vf[kk][dt]);
    }
  }

  // epilogue: out[b][i][h*64+d] fp32
  #pragma unroll
  for (int r = 0; r < 4; r++) {
    float rl = 1.0f / lrow[r];
    #pragma unroll
    for (int dt = 0; dt < 4; dt++) {
      int i = i0 + arow + q4 * 4 + r;
      int d = dt * 16 + cc;
      out[((size_t)b * S + i) * HID + h * 64 + d] = Oc[dt][r] * rl;
    }
  }
#undef LDP
#undef LDK
#undef GT
#undef HT
#undef CT
}

// ---------------- launch ----------------
extern "C" void kernel_launch(void* const* d_in, const int* in_sizes, int n_in,
                              void* d_out, int out_size, void* d_ws, size_t ws_size,
                              hipStream_t stream) {
  const float* hs   = (const float*)d_in[0];
  const float* mask = (const float*)d_in[1];
  // d_in[2] relative_pos == i-j analytically (never clamps for S=512, span 512)
  const float* Wq  = (const float*)d_in[3];
  const float* bq  = (const float*)d_in[4];
  const float* Wk  = (const float*)d_in[5];
  const float* bk  = (const float*)d_in[6];
  const float* Wv  = (const float*)d_in[7];
  const float* bv  = (const float*)d_in[8];
  const float* Wpk = (const float*)d_in[9];
  const float* bpk = (const float*)d_in[10];
  const float* rel = (const float*)d_in[11];
  float* out = (float*)d_out;

  char* ws = (char*)d_ws;
  __bf16* cb   = (__bf16*)ws;                      // casts: X|Wq|Wk|Wv|Wpk|rel = 18 MB
  __bf16* Xb   = cb;
  __bf16* Wqb  = cb + 4194304;
  __bf16* Wkb  = cb + 5242880;
  __bf16* Wvb  = cb + 6291456;
  __bf16* Wpkb = cb + 7340032;
  __bf16* Rb   = cb + 8388608;
  __bf16* qb   = (__bf16*)(ws + 18874368);         // [b][h][s][d] 8 MB (pre-scaled)
  __bf16* kb   = (__bf16*)(ws + 27262976);         // [b][h][s][d] 8 MB
  __bf16* vtb  = (__bf16*)(ws + 35651584);         // [b][h][d][s] 8 MB
  __bf16* posb = (__bf16*)(ws + 44040192);         // [h][p][d]    2 MB (pre-scaled)

  castall<<<9216, 256, 0, stream>>>(hs, Wq, Wk, Wv, Wpk, rel, cb);

  proj_gemm<<<dim3(32, 8, 4), 256, 0, stream>>>(Xb, Rb, Wqb, Wkb, Wvb, Wpkb,
                                                bq, bk, bv, bpk, qb, kb, vtb, posb);

  attn<<<dim3(4, 128), 512, 0, stream>>>(qb, kb, vtb, posb, mask, out);
}

// Round 7
// 251.915 us; speedup vs baseline: 1.6723x; 1.6723x over previous
//
#include <hip/hip_runtime.h>
#include <cstdint>
#include <cstddef>

// ---------------- problem constants ----------------
static constexpr int NB  = 8;     // batch
static constexpr int S   = 512;   // seq len
static constexpr int HID = 1024;
static constexpr int NH  = 16;    // heads
static constexpr int DH  = 64;    // head dim
static constexpr int P2  = 1024;  // 2*ATT_SPAN

static constexpr float INV_S1 = 0.14433756729740643f;  // 1/sqrt(3*H)

typedef __bf16 v8bf  __attribute__((ext_vector_type(8)));
typedef __bf16 v4bf  __attribute__((ext_vector_type(4)));
typedef float  f32x4 __attribute__((ext_vector_type(4)));

#define MFMA16(acc, a, b) acc = __builtin_amdgcn_mfma_f32_16x16x32_bf16(a, b, acc, 0, 0, 0)

// direct global->LDS DMA, 16B per lane; LDS dest = uniform base + lane*16
#define GLOAD_LDS16(gp, lp) __builtin_amdgcn_global_load_lds( \
    (const __attribute__((address_space(1))) void*)(gp), \
    (__attribute__((address_space(3))) void*)(lp), 16, 0, 0)

// ---------------- fused cast fp32 -> bf16 over all 6 inputs ----------------
__global__ void castall(const float* __restrict__ x,  const float* __restrict__ wq,
                        const float* __restrict__ wk, const float* __restrict__ wv,
                        const float* __restrict__ wpk, const float* __restrict__ rel,
                        __bf16* __restrict__ ob) {
  size_t e = ((size_t)blockIdx.x * 256 + threadIdx.x) * 4;
  if (e >= 9437184) return;
  const float* src; size_t off;
  if (e < 4194304) { src = x; off = e; }
  else {
    int r = (int)((e - 4194304) >> 20);
    off = (e - 4194304) & 1048575;
    src = (r == 0) ? wq : (r == 1) ? wk : (r == 2) ? wv : (r == 3) ? wpk : rel;
  }
  float4 v = *(const float4*)(src + off);
  v4bf o;
  o[0] = (__bf16)v.x; o[1] = (__bf16)v.y; o[2] = (__bf16)v.z; o[3] = (__bf16)v.w;
  *(v4bf*)(ob + e) = o;
}

// ---------------- projection GEMM, bf16, BK=64, global_load_lds staging ------
__launch_bounds__(256, 4)
__global__ void proj_gemm(const __bf16* __restrict__ Xb, const __bf16* __restrict__ Rb,
                          const __bf16* __restrict__ Wqb, const __bf16* __restrict__ Wkb,
                          const __bf16* __restrict__ Wvb, const __bf16* __restrict__ Wpkb,
                          const float* __restrict__ bq, const float* __restrict__ bk_,
                          const float* __restrict__ bv_, const float* __restrict__ bpk,
                          __bf16* __restrict__ qo, __bf16* __restrict__ ko,
                          __bf16* __restrict__ vto, __bf16* __restrict__ po) {
  const int z = blockIdx.z;
  const __bf16* A; const __bf16* W; const float* bias; __bf16* out; int M; float osc;
  if      (z == 0) { A = Xb; W = Wqb;  bias = bq;  out = qo;  M = 4096; osc = INV_S1; }
  else if (z == 1) { A = Xb; W = Wkb;  bias = bk_; out = ko;  M = 4096; osc = 1.0f; }
  else if (z == 2) { A = Xb; W = Wvb;  bias = bv_; out = vto; M = 4096; osc = 1.0f; }
  else             { A = Rb; W = Wpkb; bias = bpk; out = po;  M = 1024; osc = INV_S1; }
  const int m0 = blockIdx.x * 128;
  if (m0 >= M) return;
  const int n0 = blockIdx.y * 128;
  const int K = 1024;

  __shared__ __bf16 Al[128 * 64];  // unpadded; phys seg = seg ^ (row&7)
  __shared__ __bf16 Bl[128 * 64];

  const int t = threadIdx.x;
  const int w = t >> 6, lane = t & 63, q4 = lane >> 4, cc = lane & 15;
  const int wm = w >> 1, wn = w & 1;
  const int srow_in = lane >> 3;
  const int sseg    = ((lane & 7) ^ srow_in) * 8;

  f32x4 acc[4][4] = {};

  for (int k0 = 0; k0 < K; k0 += 64) {
    __syncthreads();
    #pragma unroll
    for (int i = 0; i < 4; i++) {
      int rr = w * 32 + i * 8;
      int gr = rr + srow_in;
      GLOAD_LDS16(&A[(size_t)(m0 + gr) * K + k0 + sseg], &Al[rr * 64]);
      GLOAD_LDS16(&W[(size_t)(n0 + gr) * K + k0 + sseg], &Bl[rr * 64]);
    }
    __syncthreads();
    #pragma unroll
    for (int kk = 0; kk < 2; kk++) {
      v8bf af[4], bfg[4];
      const int phys = ((4 * kk + q4) ^ (cc & 7)) * 8;
      #pragma unroll
      for (int mt = 0; mt < 4; mt++)
        af[mt] = *(const v8bf*)(&Al[(wm * 64 + mt * 16 + cc) * 64 + phys]);
      #pragma unroll
      for (int nt = 0; nt < 4; nt++)
        bfg[nt] = *(const v8bf*)(&Bl[(wn * 64 + nt * 16 + cc) * 64 + phys]);
      #pragma unroll
      for (int mt = 0; mt < 4; mt++)
        #pragma unroll
        for (int nt = 0; nt < 4; nt++)
          MFMA16(acc[mt][nt], af[mt], bfg[nt]);
    }
  }

  #pragma unroll
  for (int mt = 0; mt < 4; mt++) {
    #pragma unroll
    for (int nt = 0; nt < 4; nt++) {
      int n = n0 + wn * 64 + nt * 16 + cc;
      float bsv = bias[n];
      if (z == 2) {
        int m_base = m0 + wm * 64 + mt * 16 + q4 * 4;
        int bb = m_base >> 9, ss = m_base & 511, hh = n >> 6, dd = n & 63;
        v4bf st;
        st[0] = (__bf16)(acc[mt][nt][0] + bsv);
        st[1] = (__bf16)(acc[mt][nt][1] + bsv);
        st[2] = (__bf16)(acc[mt][nt][2] + bsv);
        st[3] = (__bf16)(acc[mt][nt][3] + bsv);
        *(v4bf*)(&out[(((size_t)bb * 16 + hh) * 64 + dd) * 512 + ss]) = st;
      } else {
        #pragma unroll
        for (int r = 0; r < 4; r++) {
          int m = m0 + wm * 64 + mt * 16 + q4 * 4 + r;
          float val = (acc[mt][nt][r] + bsv) * osc;
          size_t idx;
          if (z < 2)
            idx = ((size_t)(m >> 9) * 16 + (n >> 6)) * (512 * 64) + (size_t)(m & 511) * 64 + (n & 63);
          else
            idx = (size_t)(n >> 6) * (1024 * 64) + (size_t)m * 64 + (n & 63);
          out[idx] = (__bf16)val;
        }
      }
    }
  }
}

// ---------------- fused disentangled attention: j-split, zero barriers -------
// grid (8, 128, 2): blockIdx.x = 64-row i-block, y = bh, z = j-half.
// 256 threads = 4 free-running waves; wave w owns i-rows [i0+16w, i0+16w+16).
// Each block processes jt in [4z, 4z+4) with its own online softmax, then
// stores normalized partial O (bf16) + (m,l) to ws; combine kernel merges.
// Q,pos pre-scaled by 1/sqrt(48); G carries residual sqrt(3)/2.
__launch_bounds__(256, 4)
__global__ void attn(const __bf16* __restrict__ qb, const __bf16* __restrict__ kb,
                     const __bf16* __restrict__ vtb, const __bf16* __restrict__ posb,
                     const float* __restrict__ mask,
                     __bf16* __restrict__ Op, float2* __restrict__ lm) {
  const int bh = blockIdx.y, b = bh >> 4, h = bh & 15;
  const int i0 = blockIdx.x * 64;
  const int jh = blockIdx.z;

  __shared__ __bf16 Sb[64 * 136];   // [a][slot]: G at jj*2, H at jj*2+1, probs at 0..63

  const int t = threadIdx.x, w = t >> 6, lane = t & 63, q4 = lane >> 4, cc = lane & 15;
  const int arow = w * 16;
  const size_t bho = (size_t)bh * (S * DH);
  const __bf16* qp  = qb  + bho;
  const __bf16* kp  = kb  + bho;
  const __bf16* vtp = vtb + bho;   // [d][s]
  const __bf16* pp  = posb + (size_t)h * (P2 * DH);

  v8bf aq0 = *(const v8bf*)(&qp[(size_t)(i0 + arow + cc) * DH + q4 * 8]);
  v8bf aq1 = *(const v8bf*)(&qp[(size_t)(i0 + arow + cc) * DH + 32 + q4 * 8]);

  f32x4 Oc[4] = {};
  float mrow[4], lrow[4];
  #pragma unroll
  for (int r = 0; r < 4; r++) { mrow[r] = -__builtin_inff(); lrow[r] = 0.f; }

#define LDP(d0, d1, U) { int p_ = pw0 + 16 * (U) + cc; p_ = min(max(p_, 0), P2 - 1); \
  const __bf16* pr_ = &pp[(size_t)p_ * DH + q4 * 8]; \
  d0 = *(const v8bf*)pr_; d1 = *(const v8bf*)(pr_ + 32); }
#define LDK(d0, d1, NT) { const __bf16* kr_ = &kp[(size_t)(j0 + (NT) * 16 + cc) * DH + q4 * 8]; \
  d0 = *(const v8bf*)kr_; d1 = *(const v8bf*)(kr_ + 32); }
#define GT(U, P0, P1) { f32x4 g_ = {}; MFMA16(g_, aq0, P0); MFMA16(g_, aq1, P1); \
  _Pragma("unroll") for (int r_ = 0; r_ < 4; r_++) { \
    int jj_ = q4 * 4 + r_ - 16 * (U) - cc + 63; \
    if ((unsigned)jj_ < 64u) Sb[(arow + q4 * 4 + r_) * 136 + jj_ * 2] = (__bf16)(g_[r_] * 0.8660254f); } }
#define HT(U, NT, P0, P1, K0, K1) { f32x4 h_ = {}; MFMA16(h_, P0, K0); MFMA16(h_, P1, K1); \
  _Pragma("unroll") for (int r_ = 0; r_ < 4; r_++) { \
    int ar_ = 16 * (U) + q4 * 4 + r_ + 16 * (NT) + cc - 63; \
    if ((unsigned)ar_ < 16u) Sb[(arow + ar_) * 136 + (16 * (NT) + cc) * 2 + 1] = (__bf16)h_[r_]; } }
#define CT(NT, K0, K1) { f32x4 c_ = {}; MFMA16(c_, aq0, K0); MFMA16(c_, aq1, K1); accc[NT] = c_; }

  for (int jt = jh * 4; jt < jh * 4 + 4; jt++) {
    const int j0 = jt * 64;
    const int pw0 = i0 + arow - j0 + 449;

    float mk[4];
    #pragma unroll
    for (int nt = 0; nt < 4; nt++) mk[nt] = mask[(size_t)b * S + j0 + nt * 16 + cc];

    f32x4 accc[4];
    v8bf p40,p41,p30,p31,p20,p21,p10,p11,p00,p01;
    v8bf k00,k01,k10,k11,k20,k21,k30,k31;

    LDP(p40, p41, 4); LDK(k00, k01, 0);
    LDP(p30, p31, 3); LDK(k10, k11, 1);
    GT(4, p40, p41); HT(4, 0, p40, p41, k00, k01); CT(0, k00, k01);
    LDP(p20, p21, 2); LDK(k20, k21, 2);
    GT(3, p30, p31); HT(3, 0, p30, p31, k00, k01); HT(3, 1, p30, p31, k10, k11); CT(1, k10, k11);
    LDP(p10, p11, 1); LDK(k30, k31, 3);
    GT(2, p20, p21); HT(2, 1, p20, p21, k10, k11); HT(2, 2, p20, p21, k20, k21); CT(2, k20, k21);
    LDP(p00, p01, 0);
    GT(1, p10, p11); HT(1, 2, p10, p11, k20, k21); HT(1, 3, p10, p11, k30, k31); CT(3, k30, k31);
    GT(0, p00, p01); HT(0, 3, p00, p01, k30, k31);

    float sc[4][4];
    float tmax[4] = { -__builtin_inff(), -__builtin_inff(), -__builtin_inff(), -__builtin_inff() };
    #pragma unroll
    for (int nt = 0; nt < 4; nt++) {
      int jj = nt * 16 + cc;
      #pragma unroll
      for (int r = 0; r < 4; r++) {
        const __bf16* slot = &Sb[(arow + q4 * 4 + r) * 136 + jj * 2];
        float s = accc[nt][r] + (float)slot[0] + (float)slot[1] + mk[nt];
        sc[nt][r] = s;
        tmax[r] = fmaxf(tmax[r], s);
      }
    }
    #pragma unroll
    for (int off = 1; off < 16; off <<= 1)
      #pragma unroll
      for (int r = 0; r < 4; r++) tmax[r] = fmaxf(tmax[r], __shfl_xor(tmax[r], off, 64));

    v8bf vf[2][4];
    #pragma unroll
    for (int kk = 0; kk < 2; kk++)
      #pragma unroll
      for (int dt = 0; dt < 4; dt++)
        vf[kk][dt] = *(const v8bf*)(&vtp[(size_t)(dt * 16 + cc) * S + j0 + kk * 32 + q4 * 8]);

    float alpha[4], psum[4];
    #pragma unroll
    for (int r = 0; r < 4; r++) {
      float mnew = fmaxf(mrow[r], tmax[r]);
      alpha[r] = __expf(mrow[r] - mnew);
      mrow[r] = mnew;
      psum[r] = 0.f;
    }
    #pragma unroll
    for (int nt = 0; nt < 4; nt++)
      #pragma unroll
      for (int r = 0; r < 4; r++) {
        float p = __expf(sc[nt][r] - mrow[r]);
        psum[r] += p;
        Sb[(arow + q4 * 4 + r) * 136 + nt * 16 + cc] = (__bf16)p;
      }
    #pragma unroll
    for (int off = 1; off < 16; off <<= 1)
      #pragma unroll
      for (int r = 0; r < 4; r++) psum[r] += __shfl_xor(psum[r], off, 64);
    #pragma unroll
    for (int r = 0; r < 4; r++) lrow[r] = lrow[r] * alpha[r] + psum[r];
    #pragma unroll
    for (int dt = 0; dt < 4; dt++)
      #pragma unroll
      for (int r = 0; r < 4; r++) Oc[dt][r] *= alpha[r];

    #pragma unroll
    for (int kk = 0; kk < 2; kk++) {
      v8bf ap = *(const v8bf*)(&Sb[(arow + cc) * 136 + kk * 32 + q4 * 8]);
      #pragma unroll
      for (int dt = 0; dt < 4; dt++)
        MFMA16(Oc[dt], ap, vf[kk][dt]);
    }
  }

  // epilogue: normalized partial O (bf16) + (m,l) per row
  const size_t plane = (size_t)jh * (128 * S);
  #pragma unroll
  for (int r = 0; r < 4; r++) {
    int i = i0 + arow + q4 * 4 + r;
    float rl = 1.0f / lrow[r];
    if (cc == 0) lm[plane + (size_t)bh * S + i] = make_float2(mrow[r], lrow[r]);
    #pragma unroll
    for (int dt = 0; dt < 4; dt++)
      Op[(plane + (size_t)bh * S + i) * 64 + dt * 16 + cc] = (__bf16)(Oc[dt][r] * rl);
  }
#undef LDP
#undef LDK
#undef GT
#undef HT
#undef CT
}

// ---------------- combine the two j-half partials ----------------
__global__ void combine(const __bf16* __restrict__ Op, const float2* __restrict__ lm,
                        float* __restrict__ out) {
  int tg = blockIdx.x * 256 + threadIdx.x;          // [0, 128*512*16)
  int gi = tg >> 4;                                 // bh*512 + i
  int d4 = (tg & 15) * 4;
  int bh = gi >> 9, i = gi & 511, b = bh >> 4, h = bh & 15;
  float2 a = lm[gi];
  float2 c = lm[65536 + gi];
  float mmax = fmaxf(a.x, c.x);
  float w0 = __expf(a.x - mmax) * a.y;
  float w1 = __expf(c.x - mmax) * c.y;
  float inv = 1.0f / (w0 + w1);
  w0 *= inv; w1 *= inv;
  v4bf o0 = *(const v4bf*)(&Op[(size_t)gi * 64 + d4]);
  v4bf o1 = *(const v4bf*)(&Op[(size_t)(4194304) + (size_t)gi * 64 + d4]);
  float4 res;
  res.x = w0 * (float)o0[0] + w1 * (float)o1[0];
  res.y = w0 * (float)o0[1] + w1 * (float)o1[1];
  res.z = w0 * (float)o0[2] + w1 * (float)o1[2];
  res.w = w0 * (float)o0[3] + w1 * (float)o1[3];
  *(float4*)(&out[((size_t)b * S + i) * HID + h * 64 + d4]) = res;
}

// ---------------- launch ----------------
extern "C" void kernel_launch(void* const* d_in, const int* in_sizes, int n_in,
                              void* d_out, int out_size, void* d_ws, size_t ws_size,
                              hipStream_t stream) {
  const float* hs   = (const float*)d_in[0];
  const float* mask = (const float*)d_in[1];
  const float* Wq  = (const float*)d_in[3];
  const float* bq  = (const float*)d_in[4];
  const float* Wk  = (const float*)d_in[5];
  const float* bk  = (const float*)d_in[6];
  const float* Wv  = (const float*)d_in[7];
  const float* bv  = (const float*)d_in[8];
  const float* Wpk = (const float*)d_in[9];
  const float* bpk = (const float*)d_in[10];
  const float* rel = (const float*)d_in[11];
  float* out = (float*)d_out;

  char* ws = (char*)d_ws;
  __bf16* cb   = (__bf16*)ws;                      // casts: X|Wq|Wk|Wv|Wpk|rel = 18 MB
  __bf16* Xb   = cb;
  __bf16* Wqb  = cb + 4194304;
  __bf16* Wkb  = cb + 5242880;
  __bf16* Wvb  = cb + 6291456;
  __bf16* Wpkb = cb + 7340032;
  __bf16* Rb   = cb + 8388608;
  __bf16* qb   = (__bf16*)(ws + 18874368);         // [b][h][s][d] 8 MB (pre-scaled)
  __bf16* kb   = (__bf16*)(ws + 27262976);         // [b][h][s][d] 8 MB
  __bf16* vtb  = (__bf16*)(ws + 35651584);         // [b][h][d][s] 8 MB
  __bf16* posb = (__bf16*)(ws + 44040192);         // [h][p][d]    2 MB (pre-scaled)
  // partials overlay the dead cast region (cast/proj finish with cb before attn)
  __bf16* Op   = (__bf16*)ws;                      // [2][128][512][64] bf16 = 16 MB
  float2* lm   = (float2*)(ws + 16777216);         // [2][128][512] float2 = 1 MB

  castall<<<9216, 256, 0, stream>>>(hs, Wq, Wk, Wv, Wpk, rel, cb);

  proj_gemm<<<dim3(32, 8, 4), 256, 0, stream>>>(Xb, Rb, Wqb, Wkb, Wvb, Wpkb,
                                                bq, bk, bv, bpk, qb, kb, vtb, posb);

  attn<<<dim3(8, 128, 2), 256, 0, stream>>>(qb, kb, vtb, posb, mask, Op, lm);

  combine<<<4096, 256, 0, stream>>>(Op, lm, out);
}